// Round 10
// baseline (2025592.773 us; speedup 1.0000x reference)
//
#include <hip/hip_runtime.h>
#include <cstdint>

using u16 = unsigned short;
using u32 = unsigned int;
using u64 = unsigned long long;

typedef __bf16 bf16x8 __attribute__((ext_vector_type(8)));
typedef float  f32x4  __attribute__((ext_vector_type(4)));
typedef unsigned int u32x4 __attribute__((ext_vector_type(4)));

#define WPITCH 2064
#define SCAN_LDS 125696
#define YG_LDS   147456

__device__ __forceinline__ float b2f(u16 u) {
    u32 i = ((u32)u) << 16; float f; __builtin_memcpy(&f, &i, 4); return f;
}
__device__ __forceinline__ u16 f2b(float f) {
    u32 i; __builtin_memcpy(&i, &f, 4);
    u32 r = (i + 0x7FFFu + ((i >> 16) & 1u)) >> 16; return (u16)r;
}
__device__ __forceinline__ uint4 pack8f(const float* f) {
    u16 t[8];
#pragma unroll
    for (int j = 0; j < 8; ++j) t[j] = f2b(f[j]);
    uint4 r; __builtin_memcpy(&r, t, 16); return r;
}

// ---------------------------------------------------------------------------
// Persistent GRU scan, one layer, 512 steps. 256 WGs x 512 thr, 1 WG/CU.
// Robust XCD-local groups: two-phase registration builds a BIJECTIVE
// (grp, rank) assignment from per-XCD arrival order (works for ANY WG->XCD
// distribution). Groups fully inside one XCD sync via sc0 (local L2);
// straddling groups fall back to sc0 sc1 (fabric). Bounded polls convert
// any sync failure into wrong-data (diagnosable) instead of a hang.
// ---------------------------------------------------------------------------
__global__ __launch_bounds__(512) void gru_scan(
    const float* __restrict__ xin,   // rows (b*512+t)*1024
    const float* __restrict__ Wxz, const float* __restrict__ Wxr,
    const float* __restrict__ Wxg,
    const float* __restrict__ Whz, const float* __restrict__ Whr,
    const float* __restrict__ Whg,
    const float* __restrict__ bzp, const float* __restrict__ brp,
    const float* __restrict__ bgp,
    float* __restrict__ hout,        // [b][t][1024] f32 (d_out y-region)
    float* __restrict__ hidden,      // [b][2][1024] f32 (d_out tail)
    u16* __restrict__ hbg,           // [8 grp][2 par][8][1024] bf16
    u16* __restrict__ rbg,           // [8 grp][2 par][8][1024] bf16
    u32* __restrict__ flags,         // [8 grp][2 phase][2 par][1024]
    u32* __restrict__ regc,          // [16]: cnt[0..7], total at [8]
    int layer, int eb)
{
    extern __shared__ char sm[];
    char*  hs    = sm;                     // 33024: h/rh stage, 16 rows x 2064
    char*  scZ   = sm + 33024;             // 32768: GEMV partials (4 slots)
    char*  xb0   = sm + 65792;             // 16384: x-stage buf0 (A 4096 | W 12288)
    char*  xb1   = sm + 82176;             // 16384
    float* xls   = (float*)(sm + 98560);   // 24576: [2][4t][8b][96]
    float* gts   = (float*)(sm + 123136);  // 1024
    float* hwn   = (float*)(sm + 124160);  // 1024
    u16*   tmp16 = (u16*)(sm + 125184);    // 512

    const long wbase = (long)layer * 1048576;
    const long bbase = (long)layer * 1024;
    const int tid  = threadIdx.x;
    const int lane = tid & 63;
    const int wv   = tid >> 6;

    // ---- robust XCD-local group formation --------------------------------
    u32 xcc;
    asm("s_getreg_b32 %0, hwreg(HW_REG_XCC_ID)" : "=s"(xcc));
    xcc &= 7;
    volatile u32* bc = (volatile u32*)scZ;
    if (tid == 0) {
        u32 r = __hip_atomic_fetch_add(regc + xcc, 1u, __ATOMIC_RELAXED,
                                       __HIP_MEMORY_SCOPE_AGENT);
        __hip_atomic_fetch_add(regc + 8, 1u, __ATOMIC_ACQ_REL,
                               __HIP_MEMORY_SCOPE_AGENT);
        int itc = 0;
        while (__hip_atomic_load(regc + 8, __ATOMIC_ACQUIRE,
                                 __HIP_MEMORY_SCOPE_AGENT) < 256u) {
            __builtin_amdgcn_s_sleep(8);
            if (++itc > (1 << 17)) break;   // safety: never hang
        }
        u32 pre = 0, cx = 0;
        for (u32 x = 0; x < 8; ++x) {
            u32 c = __hip_atomic_load(regc + x, __ATOMIC_RELAXED,
                                      __HIP_MEMORY_SCOPE_AGENT);
            if (x < xcc) pre += c;
            if (x == xcc) cx = c;
        }
        u32 G = pre + r;
        u32 g = G >> 5;
        bc[0] = g;
        bc[1] = G & 31;
        bc[2] = (g * 32 >= pre && g * 32 + 32 <= pre + cx) ? 1u : 0u;
    }
    __syncthreads();
    const int grp = (int)bc[0];
    const int w   = (int)bc[1];
    const int sys = bc[2] ? 0 : 1;     // 1 -> fabric-scope sync needed
    __syncthreads();

    const int bg0 = grp * 8;
    const int n0w = w * 32;
    char* hbG = (char*)hbg + grp * 32768;   // [2 par][16384]
    char* rbG = (char*)rbg + grp * 32768;
    u32*  flg = flags + grp * 4096;         // [phase][par][1024]

    // ---- recurrent weights -> VGPR B-fragments
    bf16x8 wZ[2][4], wR[2][4], wG[2][4];
#pragma unroll
    for (int nt = 0; nt < 2; ++nt) {
#pragma unroll
        for (int i = 0; i < 4; ++i) {
            const int k0  = wv * 128 + i * 32 + ((lane >> 4) << 3);
            const int col = n0w + nt * 16 + (lane & 15);
            u16 ez[8], er[8], eg[8];
#pragma unroll
            for (int j = 0; j < 8; ++j) {
                long o = wbase + (long)(k0 + j) * 1024 + col;
                ez[j] = f2b(Whz[o]); er[j] = f2b(Whr[o]); eg[j] = f2b(Whg[o]);
            }
            __builtin_memcpy(&wZ[nt][i], ez, 16);
            __builtin_memcpy(&wR[nt][i], er, 16);
            __builtin_memcpy(&wG[nt][i], eg, 16);
        }
    }

    // zero hs rows 8..15 once (MFMA A rows 8-15 feed discarded C rows)
    for (int u = tid; u < 2064; u += 512)
        *(u64*)(hs + 8 * WPITCH + u * 8) = 0ull;

    const int b8   = tid >> 6;          // batch 0..7 (z,r mapping)
    const int gate = (tid >> 5) & 1;    // 0=z 1=r
    const int n32  = tid & 31;          // col 0..31
    const int ntb  = n32 >> 4, nnb = n32 & 15;
    const float biasZR = (gate ? brp : bzp)[bbase + n0w + n32];
    const int gb = tid >> 5, gn = tid & 31;     // g mapping (tid<256)
    const float biasG = (tid < 256) ? bgp[bbase + n0w + gn] : 0.f;

    // ---- helpers ---------------------------------------------------------
    auto XLOAD = [&](int kt, int wt0, f32x4& ra, f32x4* rw) {
        int r = tid >> 4, j = tid & 15;
        ra = *(const f32x4*)(xin +
              ((long)(bg0 + (r & 7)) * 512 + (wt0 + (r >> 3))) * 1024 +
              kt * 64 + j * 4);
        if (tid >= 128) {
            int u = tid - 128, g3 = u >> 7, rem = u & 127, k = rem >> 1,
                half = rem & 1;
            const float* Wp = (g3 == 0 ? Wxz : (g3 == 1 ? Wxr : Wxg)) + wbase +
                              (long)(kt * 64 + k) * 1024 + n0w + half * 16;
            rw[0] = *(const f32x4*)(Wp);
            rw[1] = *(const f32x4*)(Wp + 4);
            rw[2] = *(const f32x4*)(Wp + 8);
            rw[3] = *(const f32x4*)(Wp + 12);
        }
    };
    auto XSTORE = [&](char* xb, const f32x4& ra, const f32x4* rw) {
        char* hsA = xb; char* hsW = xb + 4096;
        int r = tid >> 4, j = tid & 15;
        u16 e[4];
#pragma unroll
        for (int q = 0; q < 4; ++q) e[q] = f2b(ra[q]);
        u64 v; __builtin_memcpy(&v, e, 8);
        *(u64*)(hsA + r * 128 + ((j * 8) ^ ((r & 7) << 4))) = v;
        if (tid >= 128) {
            int u = tid - 128, g3 = u >> 7, rem = u & 127, k = rem >> 1,
                half = rem & 1;
#pragma unroll
            for (int c = 0; c < 16; ++c) {
                int row = g3 * 32 + half * 16 + c;
                *(u16*)(hsW + row * 128 + ((k * 2) ^ ((row & 7) << 4))) =
                    f2b(rw[c >> 2][c & 3]);
            }
        }
    };
    f32x4 aX0 = {0,0,0,0}, aX1 = {0,0,0,0};
    auto XMFMA = [&](char* xb) {
        char* hsA = xb; char* hsW = xb + 4096;
#pragma unroll
        for (int ks = 0; ks < 2; ++ks) {
            int kb = ks * 64 + ((lane >> 4) << 4);
            int ar = (wv & 1) * 16 + (lane & 15);
            bf16x8 aF = *(const bf16x8*)(hsA + ar * 128 + (kb ^ ((ar & 7) << 4)));
            int br0 = (wv >> 1) * 16 + (lane & 15);
            bf16x8 bF0 = *(const bf16x8*)(hsW + br0 * 128 + (kb ^ ((br0 & 7) << 4)));
            aX0 = __builtin_amdgcn_mfma_f32_16x16x32_bf16(aF, bF0, aX0, 0, 0, 0);
            if (wv < 4) {
                int br1 = ((wv >> 1) + 4) * 16 + (lane & 15);
                bf16x8 bF1 = *(const bf16x8*)(hsW + br1 * 128 + (kb ^ ((br1 & 7) << 4)));
                aX1 = __builtin_amdgcn_mfma_f32_16x16x32_bf16(aF, bF1, aX1, 0, 0, 0);
            }
        }
    };
    auto XCOMPUTE = [&](const f32x4& raA, const f32x4* rwA,
                        const f32x4& raB, const f32x4* rwB) {
        XSTORE(xb0, raA, rwA);
        __syncthreads();
        XMFMA(xb0);
        XSTORE(xb1, raB, rwB);
        __syncthreads();
        XMFMA(xb1);
    };
    auto XWRITE = [&](int buf) {
#pragma unroll
        for (int q = 0; q < 4; ++q) {
            int row = (wv & 1) * 16 + ((lane >> 4) << 2) + q;
            int tl = row >> 3, b = row & 7;
            xls[buf * 3072 + tl * 768 + b * 96 + (wv >> 1) * 16 + (lane & 15)] = aX0[q];
            if (wv < 4)
                xls[buf * 3072 + tl * 768 + b * 96 + ((wv >> 1) + 4) * 16 + (lane & 15)] = aX1[q];
        }
        aX0 = (f32x4){0,0,0,0}; aX1 = (f32x4){0,0,0,0};
    };
    auto STAGE_HS16 = [&](const char* src) {   // 16KB exchange -> hs
        const char* p0 = src + tid * 16;
        const char* p1 = p0 + 8192;
        u32x4 a, b;
        if (sys) {
            asm volatile(
                "global_load_dwordx4 %0, %2, off sc0 sc1\n\t"
                "global_load_dwordx4 %1, %3, off sc0 sc1\n\t"
                "s_waitcnt vmcnt(0)"
                : "=&v"(a), "=&v"(b) : "v"(p0), "v"(p1) : "memory");
        } else {
            asm volatile(
                "global_load_dwordx4 %0, %2, off sc0\n\t"
                "global_load_dwordx4 %1, %3, off sc0\n\t"
                "s_waitcnt vmcnt(0)"
                : "=&v"(a), "=&v"(b) : "v"(p0), "v"(p1) : "memory");
        }
        int i0 = tid, i1 = tid + 512;
        *(u32x4*)(hs + (i0 >> 7) * WPITCH +
                  (((i0 & 127) * 16) ^ (((i0 >> 7) & 7) << 4))) = a;
        *(u32x4*)(hs + (i1 >> 7) * WPITCH +
                  (((i1 & 127) * 16) ^ (((i1 >> 7) & 7) << 4))) = b;
    };
    auto PUBLISH = [&](char* dst, int par) {   // 512B slice, 32 lanes x 16B
        if (tid < 32) {
            int b = tid >> 2, q = tid & 3;
            u16 e[8];
#pragma unroll
            for (int j = 0; j < 8; ++j) e[j] = tmp16[b * 32 + q * 8 + j];
            u32x4 v; __builtin_memcpy(&v, e, 16);
            char* p = dst + par * 16384 + b * 2048 + n0w * 2 + q * 16;
            if (sys)
                asm volatile("global_store_dwordx4 %0, %1, off sc0 sc1"
                             :: "v"(p), "v"(v) : "memory");
            else
                asm volatile("global_store_dwordx4 %0, %1, off sc0"
                             :: "v"(p), "v"(v) : "memory");
        }
    };
    auto FLAGREL = [&](u32* fp, u32 tgtv) {   // wave0: drain data, then flag
        if (tid == 0) {
            if (sys)
                asm volatile("s_waitcnt vmcnt(0)\n\t"
                             "global_store_dword %0, %1, off sc0 sc1"
                             :: "v"(fp), "v"(tgtv) : "memory");
            else
                asm volatile("s_waitcnt vmcnt(0)\n\t"
                             "global_store_dword %0, %1, off sc0"
                             :: "v"(fp), "v"(tgtv) : "memory");
        }
    };
    auto FLAGWAIT = [&](const u32* fpbase, u32 tgtv) {
        if (tid < 32) {
            const u32* fp = fpbase + tid * 16;
            u32 v; int itc = 0;
            for (;;) {
                if (sys)
                    asm volatile("global_load_dword %0, %1, off sc0 sc1\n\t"
                                 "s_waitcnt vmcnt(0)"
                                 : "=v"(v) : "v"(fp) : "memory");
                else
                    asm volatile("global_load_dword %0, %1, off sc0\n\t"
                                 "s_waitcnt vmcnt(0)"
                                 : "=v"(v) : "v"(fp) : "memory");
                if (v >= tgtv) break;
                if (++itc > 8192) break;   // bounded: fail loud, never hang
                __builtin_amdgcn_s_sleep(1);
            }
        }
        __builtin_amdgcn_sched_barrier(0);
        __syncthreads();
    };

    // ---- prologue: produce x window 0 (timesteps 0..3) into xls[0]
    {
        f32x4 raA, raB; f32x4 rwA[4], rwB[4];
        for (int kt = 0; kt < 16; kt += 2) {
            XLOAD(kt, 0, raA, rwA);
            XLOAD(kt + 1, 0, raB, rwB);
            XCOMPUTE(raA, rwA, raB, rwB);
        }
        XWRITE(0);
    }

    for (int tc = 0; tc < 512; ++tc) {
        const int p   = tc & 3;
        const int par = tc & 1;
        const int cur = (tc >> 2) & 1;
        const u32 tgt = (u32)(eb + tc + 1);
        const bool prod = (tc < 508);
        const int wt0 = (tc & ~3) + 4;

        f32x4 raA, raB; f32x4 rwA[4], rwB[4];
        if (prod) {           // issue pair-0 loads BEFORE the wait
            XLOAD(p * 4 + 0, wt0, raA, rwA);
            XLOAD(p * 4 + 1, wt0, raB, rwB);
        }

        // ---- wait h(t-1) flags, stage h
        if (tc == 0) {
            __syncthreads();
#pragma unroll
            for (int u = 0; u < 2; ++u) {
                int idx = u * 512 + tid;
                *(u32x4*)(hs + (idx >> 7) * WPITCH +
                          (((idx & 127) * 16) ^ (((idx >> 7) & 7) << 4))) =
                    (u32x4){0, 0, 0, 0};
            }
        } else {
            FLAGWAIT(flg + 2048 + ((tc - 1) & 1) * 1024, tgt - 1);
            STAGE_HS16(hbG + ((tc - 1) & 1) * 16384);
        }
        const float h_own = (tc == 0) ? 0.f : hwn[b8 * 32 + n32];
        __syncthreads();

        if (prod) XCOMPUTE(raA, rwA, raB, rwB);

        // ---- z,r GEMV (K split across 8 waves, 2 n-tiles)
        {
            f32x4 aZ0 = {0,0,0,0}, aZ1 = {0,0,0,0};
            f32x4 aR0 = {0,0,0,0}, aR1 = {0,0,0,0};
#pragma unroll
            for (int i = 0; i < 4; ++i) {
                int kby = wv * 256 + i * 64 + ((lane >> 4) << 4);
                int ar = lane & 15;
                bf16x8 aF = *(const bf16x8*)(hs + ar * WPITCH + (kby ^ ((ar & 7) << 4)));
                aZ0 = __builtin_amdgcn_mfma_f32_16x16x32_bf16(aF, wZ[0][i], aZ0, 0, 0, 0);
                aZ1 = __builtin_amdgcn_mfma_f32_16x16x32_bf16(aF, wZ[1][i], aZ1, 0, 0, 0);
                aR0 = __builtin_amdgcn_mfma_f32_16x16x32_bf16(aF, wR[0][i], aR0, 0, 0, 0);
                aR1 = __builtin_amdgcn_mfma_f32_16x16x32_bf16(aF, wR[1][i], aR1, 0, 0, 0);
            }
            *(f32x4*)(scZ + ((0 * 8 + wv) * 64 + lane) * 16) = aZ0;
            *(f32x4*)(scZ + ((1 * 8 + wv) * 64 + lane) * 16) = aZ1;
            *(f32x4*)(scZ + ((2 * 8 + wv) * 64 + lane) * 16) = aR0;
            *(f32x4*)(scZ + ((3 * 8 + wv) * 64 + lane) * 16) = aR1;
        }
        __syncthreads();

        // ---- z,r reduce -> sigmoid; r preps r*h
        float zval = 0.f;
        {
            int slot = gate * 2 + ntb, ls = ((b8 >> 2) << 4) | nnb;
            float s = 0.f;
#pragma unroll
            for (int ww = 0; ww < 8; ++ww)
                s += *(const float*)(scZ + ((slot * 8 + ww) * 64 + ls) * 16 + (b8 & 3) * 4);
            s += xls[cur * 3072 + p * 768 + b8 * 96 + gate * 32 + n32] + biasZR;
            float sig = 1.f / (1.f + __expf(-s));
            if (gate == 0) zval = sig;
            else tmp16[b8 * 32 + n32] = f2b(sig * h_own);
        }
        __syncthreads();

        PUBLISH(rbG, par);
        FLAGREL(flg + par * 1024 + w * 16, tgt);

        if (prod) {           // issue pair-1 loads BEFORE the rh wait
            XLOAD(p * 4 + 2, wt0, raA, rwA);
            XLOAD(p * 4 + 3, wt0, raB, rwB);
        }

        // ---- wait rh flags, stage r*h
        FLAGWAIT(flg + par * 1024, tgt);
        STAGE_HS16(rbG + par * 16384);
        __syncthreads();

        if (prod) XCOMPUTE(raA, rwA, raB, rwB);

        // ---- g GEMV
        {
            f32x4 aG0 = {0,0,0,0}, aG1 = {0,0,0,0};
#pragma unroll
            for (int i = 0; i < 4; ++i) {
                int kby = wv * 256 + i * 64 + ((lane >> 4) << 4);
                int ar = lane & 15;
                bf16x8 aF = *(const bf16x8*)(hs + ar * WPITCH + (kby ^ ((ar & 7) << 4)));
                aG0 = __builtin_amdgcn_mfma_f32_16x16x32_bf16(aF, wG[0][i], aG0, 0, 0, 0);
                aG1 = __builtin_amdgcn_mfma_f32_16x16x32_bf16(aF, wG[1][i], aG1, 0, 0, 0);
            }
            *(f32x4*)(scZ + ((0 * 8 + wv) * 64 + lane) * 16) = aG0;
            *(f32x4*)(scZ + ((1 * 8 + wv) * 64 + lane) * 16) = aG1;
        }
        __syncthreads();
        if (tid < 256) {
            int nt = gn >> 4, nn = gn & 15, ls = ((gb >> 2) << 4) | nn;
            float s = 0.f;
#pragma unroll
            for (int ww = 0; ww < 8; ++ww)
                s += *(const float*)(scZ + ((nt * 8 + ww) * 64 + ls) * 16 + (gb & 3) * 4);
            s += xls[cur * 3072 + p * 768 + gb * 96 + 64 + gn] + biasG;
            float e = __expf(-2.f * s);
            gts[gb * 32 + gn] = 2.f / (1.f + e) - 1.f;
        }
        __syncthreads();

        // ---- h update + publish
        if (gate == 0) {
            float gt = gts[b8 * 32 + n32];
            float hn = zval * h_own + (1.f - zval) * gt;
            hout[((long)(bg0 + b8) * 512 + tc) * 1024 + n0w + n32] = hn;
            hwn[b8 * 32 + n32]   = hn;
            tmp16[b8 * 32 + n32] = f2b(hn);
            if (tc == 511)
                hidden[(long)(bg0 + b8) * 2048 + layer * 1024 + n0w + n32] = hn;
        }
        __syncthreads();
        PUBLISH(hbG, par);
        FLAGREL(flg + 2048 + par * 1024 + w * 16, tgt);

        if (p == 3 && prod) XWRITE(cur ^ 1);
    }
}

// ---------------------------------------------------------------------------
// In-place output projection: y = h1 @ Why + by over h1 rows in d_out.
// ---------------------------------------------------------------------------
__global__ __launch_bounds__(256) void ygemm(const float* __restrict__ Why,
                                             const float* __restrict__ by,
                                             float* __restrict__ y)
{
    extern __shared__ char sm[];
    char* sA = sm;            // 64 rows x 2048B (bf16 k=1024)
    char* sW = sm + 131072;   // 128 n-rows x 128B

    const int tid  = threadIdx.x;
    const int lane = tid & 63;
    const int wv   = tid >> 6;
    const long r0  = (long)blockIdx.x * 64;

    for (int it = 0; it < 32; ++it) {
        int c = it * 256 + tid;
        int row = c >> 7, j = c & 127;
        long gi = (r0 + row) * 1024 + j * 8;
        float tp[8];
        *(uint4*)tp       = *(const uint4*)(y + gi);
        *(uint4*)(tp + 4) = *(const uint4*)(y + gi + 4);
        *(uint4*)(sA + row * 2048 + ((j * 16) ^ ((row & 7) << 4))) = pack8f(tp);
    }
    __syncthreads();

    for (int nt = 0; nt < 8; ++nt) {
        f32x4 acc[4][2] = {};
        for (int kt = 0; kt < 16; ++kt) {
            __syncthreads();
#pragma unroll
            for (int uu = 0; uu < 4; ++uu) {
                int u = uu * 256 + tid;
                int nrow = u >> 3, jc = u & 7;
                u16 e[8];
#pragma unroll
                for (int q = 0; q < 8; ++q)
                    e[q] = f2b(Why[(long)(kt * 64 + jc * 8 + q) * 1024 + nt * 128 + nrow]);
                uint4 v; __builtin_memcpy(&v, e, 16);
                *(uint4*)(sW + nrow * 128 + ((jc * 16) ^ ((nrow & 7) << 4))) = v;
            }
            __syncthreads();
#pragma unroll
            for (int ks = 0; ks < 2; ++ks) {
                int kbA = kt * 128 + ks * 64 + ((lane >> 4) << 4);
                int kbW = ks * 64 + ((lane >> 4) << 4);
#pragma unroll
                for (int cc = 0; cc < 2; ++cc) {
                    int brr = (wv * 2 + cc) * 16 + (lane & 15);
                    bf16x8 bF = *(const bf16x8*)(sW + brr * 128 + (kbW ^ ((brr & 7) << 4)));
#pragma unroll
                    for (int m = 0; m < 4; ++m) {
                        int ar = m * 16 + (lane & 15);
                        bf16x8 aF = *(const bf16x8*)(sA + ar * 2048 + (kbA ^ ((ar & 7) << 4)));
                        acc[m][cc] = __builtin_amdgcn_mfma_f32_16x16x32_bf16(
                            aF, bF, acc[m][cc], 0, 0, 0);
                    }
                }
            }
        }
#pragma unroll
        for (int cc = 0; cc < 2; ++cc) {
            int col = nt * 128 + (wv * 2 + cc) * 16 + (lane & 15);
            float bv = by[col];
#pragma unroll
            for (int m = 0; m < 4; ++m)
#pragma unroll
                for (int q = 0; q < 4; ++q) {
                    long row = r0 + m * 16 + ((lane >> 4) << 2) + q;
                    y[row * 1024 + col] = acc[m][cc][q] + bv;
                }
        }
    }
}

// ---------------------------------------------------------------------------
extern "C" void kernel_launch(void* const* d_in, const int* in_sizes, int n_in,
                              void* d_out, int out_size, void* d_ws,
                              size_t ws_size, hipStream_t stream) {
    const float* input = (const float*)d_in[0];
    const float* Wxz = (const float*)d_in[1];
    const float* Whz = (const float*)d_in[2];
    const float* bz  = (const float*)d_in[3];
    const float* Wxr = (const float*)d_in[4];
    const float* Whr = (const float*)d_in[5];
    const float* br  = (const float*)d_in[6];
    const float* Wxg = (const float*)d_in[7];
    const float* Whg = (const float*)d_in[8];
    const float* bg  = (const float*)d_in[9];
    const float* Why = (const float*)d_in[10];
    const float* by  = (const float*)d_in[11];
    (void)in_sizes; (void)n_in; (void)out_size; (void)ws_size;

    float* yreg   = (float*)d_out;            // [64][512][1024] h0/h1/y
    float* hidden = yreg + 33554432;          // [64][2][1024]

    char* ws = (char*)d_ws;
    u32* flags = (u32*)ws;                    // 131072 B [8][2][2][1024]
    u16* hbg   = (u16*)(ws + 131072);         // 262144 B [8][2][8][1024]
    u16* rbg   = (u16*)(ws + 393216);         // 262144 B
    u32* reg0  = (u32*)(ws + 655360);         // 64 B: cnt[8], total
    u32* reg1  = (u32*)(ws + 655424);         // 64 B

    hipFuncSetAttribute(reinterpret_cast<const void*>(gru_scan),
                        hipFuncAttributeMaxDynamicSharedMemorySize, SCAN_LDS);
    hipFuncSetAttribute(reinterpret_cast<const void*>(ygemm),
                        hipFuncAttributeMaxDynamicSharedMemorySize, YG_LDS);
    hipMemsetAsync(flags, 0, 131072, stream);
    hipMemsetAsync(reg0, 0, 128, stream);

    gru_scan<<<256, 512, SCAN_LDS, stream>>>(
        input, Wxz, Wxr, Wxg, Whz, Whr, Whg, bz, br, bg,
        yreg, hidden, hbg, rbg, flags, reg0, /*layer=*/0, /*eb=*/0);
    gru_scan<<<256, 512, SCAN_LDS, stream>>>(
        yreg, Wxz, Wxr, Wxg, Whz, Whr, Whg, bz, br, bg,
        yreg, hidden, hbg, rbg, flags, reg1, /*layer=*/1, /*eb=*/512);
    ygemm<<<512, 256, YG_LDS, stream>>>(Why, by, yreg);
}

// Round 11
// 11870.088 us; speedup vs baseline: 170.6468x; 170.6468x over previous
//
#include <hip/hip_runtime.h>
#include <cstdint>

using u16 = unsigned short;
using u32 = unsigned int;
using u64 = unsigned long long;

typedef __bf16 bf16x8 __attribute__((ext_vector_type(8)));
typedef float  f32x4  __attribute__((ext_vector_type(4)));
typedef unsigned int u32x4 __attribute__((ext_vector_type(4)));

#define WPITCH 2064
#define SCAN_LDS 124160
#define YG_LDS   147456
#define POLL_BOUND 32768

__device__ __forceinline__ float b2f(u16 u) {
    u32 i = ((u32)u) << 16; float f; __builtin_memcpy(&f, &i, 4); return f;
}
__device__ __forceinline__ u16 f2b(float f) {
    u32 i; __builtin_memcpy(&i, &f, 4);
    u32 r = (i + 0x7FFFu + ((i >> 16) & 1u)) >> 16; return (u16)r;
}
__device__ __forceinline__ uint4 pack8f(const float* f) {
    u16 t[8];
#pragma unroll
    for (int j = 0; j < 8; ++j) t[j] = f2b(f[j]);
    uint4 r; __builtin_memcpy(&r, t, 16); return r;
}

// ---------------------------------------------------------------------------
// Fused 2-layer persistent GRU scan, 512 steps, layer-pipelined (skew 4..8).
// 256 WGs x 512 thr (1 WG/CU): blockIdx>>7 = layer; per layer 4 groups x 32
// WGs; group owns 16 batches, WG owns 32 H-cols. Recurrent weights in VGPRs.
// h0 flows layer0 -> layer1 through a depth-8 bf16 ring in ws (sc0 sc1).
// x-projection: 2-step windows, 8 K-tiles/step, staged around the flag waits.
// Sync: R8-proven sc0 sc1 stores/loads + vmcnt-ordered per-WG epoch flags.
// Inter-layer: layer1 waits flag0>=t+4 (window readable); layer0 waits
// flag1>=t-8 before ring overwrite (exactly the read-safety condition).
// ---------------------------------------------------------------------------
__global__ __launch_bounds__(512) void gru_fused(
    const float* __restrict__ xin,   // input [64][512][1024] f32
    const float* __restrict__ Wxz, const float* __restrict__ Wxr,
    const float* __restrict__ Wxg,
    const float* __restrict__ Whz, const float* __restrict__ Whr,
    const float* __restrict__ Whg,
    const float* __restrict__ bzp, const float* __restrict__ brp,
    const float* __restrict__ bgp,
    float* __restrict__ hout,        // d_out y-region: h1 rows [b][t][1024]
    float* __restrict__ hidden,      // d_out tail [b][2][1024]
    u16* __restrict__ ring,          // [8][64][1024] bf16 (h0 pipe)
    u16* __restrict__ hb,            // [2][4][16][1024] bf16 (h exch, L1 uses)
    u16* __restrict__ rb,            // [2][4][16][1024] bf16 (rh exch)
    u32* __restrict__ flags)         // [2][4][2 phase][512] u32
{
    extern __shared__ char sm[];
    char*  hs    = sm;                     // 33024: h/rh stage, 16 x 2064
    char*  scZ   = sm + 33024;             // 32768: GEMV partials (4 slots)
    char*  xb0   = sm + 65792;             // 16384: x-stage (A 4KB | W 12KB)
    char*  xb1   = sm + 82176;             // 16384
    float* xls   = (float*)(sm + 98560);   // 24576: [2 buf][2 tl][16 b][96]
    u16*   tmp16 = (u16*)(sm + 123136);    // 1024: publish repack [16][32]

    const int tid   = threadIdx.x;
    const int lane  = tid & 63;
    const int wv    = tid >> 6;
    const int layer = blockIdx.x >> 7;
    const int id    = blockIdx.x & 127;
    const int grp   = id >> 5;
    const int w     = id & 31;
    const int bg0   = grp * 16;
    const int n0w   = w * 32;
    const long wbase = (long)layer * 1048576;
    const long bbase = (long)layer * 1024;

    u16* hbG = hb + (layer * 4 + grp) * 16384;   // [16][1024]
    u16* rbG = rb + (layer * 4 + grp) * 16384;
    u32* f_rh   = flags + ((layer * 4 + grp) * 2 + 0) * 512;
    u32* f_h    = flags + ((layer * 4 + grp) * 2 + 1) * 512;
    u32* f_h_l0 = flags + ((0 * 4 + grp) * 2 + 1) * 512;
    u32* f_h_l1 = flags + ((1 * 4 + grp) * 2 + 1) * 512;

    // ---- recurrent weights -> VGPR B-fragments (k-order matches A-read)
    bf16x8 wZ[2][4], wR[2][4], wG[2][4];
#pragma unroll
    for (int nt = 0; nt < 2; ++nt) {
#pragma unroll
        for (int i = 0; i < 4; ++i) {
            const int k0  = wv * 128 + i * 32 + ((lane >> 4) << 3);
            const int col = n0w + nt * 16 + (lane & 15);
            u16 ez[8], er[8], eg[8];
#pragma unroll
            for (int j = 0; j < 8; ++j) {
                long o = wbase + (long)(k0 + j) * 1024 + col;
                ez[j] = f2b(Whz[o]); er[j] = f2b(Whr[o]); eg[j] = f2b(Whg[o]);
            }
            __builtin_memcpy(&wZ[nt][i], ez, 16);
            __builtin_memcpy(&wR[nt][i], er, 16);
            __builtin_memcpy(&wG[nt][i], eg, 16);
        }
    }

    const int b8  = tid >> 5;           // batch 0..15
    const int n32 = tid & 31;           // col 0..31
    const int ntc = n32 >> 4, nnc = n32 & 15;
    const int ls  = ((b8 >> 2) << 4) | nnc;
    const int el  = b8 & 3;
    const float biasZ = bzp[bbase + n0w + n32];
    const float biasR = brp[bbase + n0w + n32];
    const float biasG = bgp[bbase + n0w + n32];

    // ---- x-production helpers -------------------------------------------
    f32x4 aX0 = {0,0,0,0}, aX1 = {0,0,0,0};
    const int mT0 = (wv < 6) ? 0 : 1, nT0 = (wv < 6) ? wv : wv - 6;
    const int mT1 = 1, nT1 = 2 + wv;    // valid wv<4

    auto XLOAD = [&](int kt, int wt0, f32x4& ra, u64& rav, f32x4* rw) {
        int r = tid >> 4, j = tid & 15;     // 32 rows x 16 thr, 4 elems
        if (layer == 0) {
            ra = *(const f32x4*)(xin +
                 ((long)(bg0 + (r & 15)) * 512 + (wt0 + (r >> 4))) * 1024 +
                 kt * 64 + j * 4);
        } else {
            const char* p = (const char*)ring +
                ((long)(((wt0 + (r >> 4)) & 7) * 64 + bg0 + (r & 15)) * 1024 +
                 kt * 64 + j * 4) * 2;
            asm volatile("global_load_dwordx2 %0, %1, off sc0 sc1\n\t"
                         "s_waitcnt vmcnt(0)"
                         : "=v"(rav) : "v"(p) : "memory");
        }
        if (tid >= 128) {   // W slab: 384 units (3 gates x 64 k x 2 half16)
            int u = tid - 128, g3 = u >> 7, rem = u & 127, k = rem >> 1,
                half = rem & 1;
            const float* Wp = (g3 == 0 ? Wxz : (g3 == 1 ? Wxr : Wxg)) + wbase +
                              (long)(kt * 64 + k) * 1024 + n0w + half * 16;
            rw[0] = *(const f32x4*)(Wp);
            rw[1] = *(const f32x4*)(Wp + 4);
            rw[2] = *(const f32x4*)(Wp + 8);
            rw[3] = *(const f32x4*)(Wp + 12);
        }
    };
    auto XSTORE = [&](char* xb, const f32x4& ra, u64 rav, const f32x4* rw) {
        char* sA = xb; char* sW = xb + 4096;
        int r = tid >> 4, j = tid & 15;
        u64 v;
        if (layer == 0) {
            u16 e[4];
#pragma unroll
            for (int q = 0; q < 4; ++q) e[q] = f2b(ra[q]);
            __builtin_memcpy(&v, e, 8);
        } else v = rav;
        *(u64*)(sA + r * 128 + ((j * 8) ^ ((r & 7) << 4))) = v;
        if (tid >= 128) {
            int u = tid - 128, g3 = u >> 7, rem = u & 127, k = rem >> 1,
                half = rem & 1;
#pragma unroll
            for (int c = 0; c < 16; ++c) {
                int row = g3 * 32 + half * 16 + c;
                *(u16*)(sW + row * 128 + ((k * 2) ^ ((row & 7) << 4))) =
                    f2b(rw[c >> 2][c & 3]);
            }
        }
    };
    auto XMFMA = [&](char* xb) {
        char* sA = xb; char* sW = xb + 4096;
#pragma unroll
        for (int ks = 0; ks < 2; ++ks) {
            int kb = ks * 64 + ((lane >> 4) << 4);
            {
                int ar = mT0 * 16 + (lane & 15), br_ = nT0 * 16 + (lane & 15);
                bf16x8 aF = *(const bf16x8*)(sA + ar * 128 + (kb ^ ((ar & 7) << 4)));
                bf16x8 bF = *(const bf16x8*)(sW + br_ * 128 + (kb ^ ((br_ & 7) << 4)));
                aX0 = __builtin_amdgcn_mfma_f32_16x16x32_bf16(aF, bF, aX0, 0, 0, 0);
            }
            if (wv < 4) {
                int ar = mT1 * 16 + (lane & 15), br_ = nT1 * 16 + (lane & 15);
                bf16x8 aF = *(const bf16x8*)(sA + ar * 128 + (kb ^ ((ar & 7) << 4)));
                bf16x8 bF = *(const bf16x8*)(sW + br_ * 128 + (kb ^ ((br_ & 7) << 4)));
                aX1 = __builtin_amdgcn_mfma_f32_16x16x32_bf16(aF, bF, aX1, 0, 0, 0);
            }
        }
    };
    // 4 K-tiles, first one pre-loaded into (ra,rav,rw)
    auto XP4 = [&](int kt0, int wt0, f32x4& ra, u64& rav, f32x4* rw) {
        XSTORE(xb0, ra, rav, rw);
        __syncthreads();
        XMFMA(xb0);
        XLOAD(kt0 + 1, wt0, ra, rav, rw);
        XSTORE(xb1, ra, rav, rw);
        __syncthreads();
        XMFMA(xb1);
        XLOAD(kt0 + 2, wt0, ra, rav, rw);
        XSTORE(xb0, ra, rav, rw);
        __syncthreads();
        XMFMA(xb0);
        XLOAD(kt0 + 3, wt0, ra, rav, rw);
        XSTORE(xb1, ra, rav, rw);
        __syncthreads();
        XMFMA(xb1);
    };
    auto XWRITE = [&](int buf) {
#pragma unroll
        for (int q = 0; q < 4; ++q) {
            int row = mT0 * 16 + ((lane >> 4) << 2) + q;   // tl = mT0, b = row&15
            xls[((buf * 2 + mT0) * 16 + (row & 15)) * 96 + nT0 * 16 + (lane & 15)] = aX0[q];
            if (wv < 4) {
                int row1 = 16 + ((lane >> 4) << 2) + q;
                xls[((buf * 2 + 1) * 16 + (row1 & 15)) * 96 + nT1 * 16 + (lane & 15)] = aX1[q];
            }
        }
        aX0 = (f32x4){0,0,0,0}; aX1 = (f32x4){0,0,0,0};
    };
    // ---- exchange helpers (all sc0 sc1) ---------------------------------
    auto STAGE32 = [&](const char* src) {   // 32KB [16][1024]bf16 -> hs
        u32x4 a0, a1, a2, a3;
        const char* p = src + tid * 16;
        asm volatile(
            "global_load_dwordx4 %0, %4, off sc0 sc1\n\t"
            "global_load_dwordx4 %1, %5, off sc0 sc1\n\t"
            "global_load_dwordx4 %2, %6, off sc0 sc1\n\t"
            "global_load_dwordx4 %3, %7, off sc0 sc1\n\t"
            "s_waitcnt vmcnt(0)"
            : "=&v"(a0), "=&v"(a1), "=&v"(a2), "=&v"(a3)
            : "v"(p), "v"(p + 8192), "v"(p + 16384), "v"(p + 24576)
            : "memory");
        u32x4 a[4] = {a0, a1, a2, a3};
#pragma unroll
        for (int u = 0; u < 4; ++u) {
            int idx = u * 512 + tid;
            *(u32x4*)(hs + (idx >> 7) * WPITCH +
                      (((idx & 127) * 16) ^ (((idx >> 7) & 7) << 4))) = a[u];
        }
    };
    auto PUBLISH = [&](char* dst) {   // [16][1024]bf16 slice from tmp16
        if (tid < 64) {
            int b = tid >> 2, q = tid & 3;
            u16 e[8];
#pragma unroll
            for (int j = 0; j < 8; ++j) e[j] = tmp16[b * 32 + q * 8 + j];
            u32x4 v; __builtin_memcpy(&v, e, 16);
            char* p = dst + b * 2048 + n0w * 2 + q * 16;
            asm volatile("global_store_dwordx4 %0, %1, off sc0 sc1"
                         :: "v"(p), "v"(v) : "memory");
        }
    };
    auto FLAGREL = [&](u32* fp, u32 tgtv) {
        if (tid == 0)
            asm volatile("s_waitcnt vmcnt(0)\n\t"
                         "global_store_dword %0, %1, off sc0 sc1"
                         :: "v"(fp), "v"(tgtv) : "memory");
    };
    auto FLAGWAIT = [&](const u32* fpbase, u32 tgtv) {
        if (tid < 32) {
            const u32* fp = fpbase + tid * 16;
            u32 v; int itc = 0;
            for (;;) {
                asm volatile("global_load_dword %0, %1, off sc0 sc1\n\t"
                             "s_waitcnt vmcnt(0)"
                             : "=v"(v) : "v"(fp) : "memory");
                if (v >= tgtv) break;
                if (++itc > POLL_BOUND) break;   // fail loud, never hang
                __builtin_amdgcn_s_sleep(1);
            }
        }
        __builtin_amdgcn_sched_barrier(0);
        __syncthreads();
    };

    // ---- prologue: produce x window [0,1] into xls buf 0
    {
        if (layer == 1) FLAGWAIT(f_h_l0, 2);
        f32x4 ra; u64 rav = 0; f32x4 rw[4];
        for (int kt = 0; kt < 16; kt += 4) {
            XLOAD(kt, 0, ra, rav, rw);
            XP4(kt, 0, ra, rav, rw);
        }
        __syncthreads();
        XWRITE(0);
        __syncthreads();
    }

    float h_own = 0.f;
    for (int tc = 0; tc < 512; ++tc) {
        const bool prod = (tc < 510);
        const int wt0 = (tc & ~1) + 2;
        const int kb8 = (tc & 1) * 8;
        const int buf = (tc >> 1) & 1;
        const int tl  = tc & 1;

        if (layer == 1 && (tc & 1) == 0 && prod)
            FLAGWAIT(f_h_l0, tc + 4);           // window [tc+2,tc+3] readable

        f32x4 ra; u64 rav = 0; f32x4 rw[4];
        if (prod) XLOAD(kb8 + 0, wt0, ra, rav, rw);

        // ---- h(t-1) wait + stage
        if (tc == 0) {
            __syncthreads();
#pragma unroll
            for (int u = 0; u < 4; ++u) {
                int idx = u * 512 + tid;
                *(u32x4*)(hs + (idx >> 7) * WPITCH +
                          (((idx & 127) * 16) ^ (((idx >> 7) & 7) << 4))) =
                    (u32x4){0, 0, 0, 0};
            }
        } else {
            FLAGWAIT(f_h, (u32)tc);
            if (layer == 0)
                STAGE32((const char*)ring + (((tc - 1) & 7) * 64 + bg0) * 2048);
            else
                STAGE32((const char*)hbG);
        }
        __syncthreads();

        if (prod) XP4(kb8 + 0, wt0, ra, rav, rw);

        // ---- z,r GEMV
        {
            f32x4 aZ0 = {0,0,0,0}, aZ1 = {0,0,0,0};
            f32x4 aR0 = {0,0,0,0}, aR1 = {0,0,0,0};
#pragma unroll
            for (int i = 0; i < 4; ++i) {
                int kby = wv * 256 + i * 64 + ((lane >> 4) << 4);
                int ar = lane & 15;
                bf16x8 aF = *(const bf16x8*)(hs + ar * WPITCH + (kby ^ ((ar & 7) << 4)));
                aZ0 = __builtin_amdgcn_mfma_f32_16x16x32_bf16(aF, wZ[0][i], aZ0, 0, 0, 0);
                aZ1 = __builtin_amdgcn_mfma_f32_16x16x32_bf16(aF, wZ[1][i], aZ1, 0, 0, 0);
                aR0 = __builtin_amdgcn_mfma_f32_16x16x32_bf16(aF, wR[0][i], aR0, 0, 0, 0);
                aR1 = __builtin_amdgcn_mfma_f32_16x16x32_bf16(aF, wR[1][i], aR1, 0, 0, 0);
            }
            *(f32x4*)(scZ + ((0 * 8 + wv) * 64 + lane) * 16) = aZ0;
            *(f32x4*)(scZ + ((1 * 8 + wv) * 64 + lane) * 16) = aZ1;
            *(f32x4*)(scZ + ((2 * 8 + wv) * 64 + lane) * 16) = aR0;
            *(f32x4*)(scZ + ((3 * 8 + wv) * 64 + lane) * 16) = aR1;
        }
        __syncthreads();

        // ---- z,r reduce (each thread owns (b8,n32) for both gates)
        float zval;
        {
            float sz = 0.f, sr = 0.f;
#pragma unroll
            for (int ww = 0; ww < 8; ++ww) {
                sz += *(const float*)(scZ + (((ntc)     * 8 + ww) * 64 + ls) * 16 + el * 4);
                sr += *(const float*)(scZ + (((2 + ntc) * 8 + ww) * 64 + ls) * 16 + el * 4);
            }
            const float* xrow = xls + ((buf * 2 + tl) * 16 + b8) * 96;
            sz += xrow[n32] + biasZ;
            sr += xrow[32 + n32] + biasR;
            zval = 1.f / (1.f + __expf(-sz));
            float rv = 1.f / (1.f + __expf(-sr));
            tmp16[b8 * 32 + n32] = f2b(rv * h_own);
        }
        __syncthreads();

        PUBLISH((char*)rbG);
        FLAGREL(f_rh + w * 16, (u32)(tc + 1));

        if (prod) XLOAD(kb8 + 4, wt0, ra, rav, rw);

        FLAGWAIT(f_rh, (u32)(tc + 1));
        STAGE32((const char*)rbG);
        __syncthreads();

        if (prod) XP4(kb8 + 4, wt0, ra, rav, rw);

        // ---- g GEMV
        {
            f32x4 aG0 = {0,0,0,0}, aG1 = {0,0,0,0};
#pragma unroll
            for (int i = 0; i < 4; ++i) {
                int kby = wv * 256 + i * 64 + ((lane >> 4) << 4);
                int ar = lane & 15;
                bf16x8 aF = *(const bf16x8*)(hs + ar * WPITCH + (kby ^ ((ar & 7) << 4)));
                aG0 = __builtin_amdgcn_mfma_f32_16x16x32_bf16(aF, wG[0][i], aG0, 0, 0, 0);
                aG1 = __builtin_amdgcn_mfma_f32_16x16x32_bf16(aF, wG[1][i], aG1, 0, 0, 0);
            }
            *(f32x4*)(scZ + ((0 * 8 + wv) * 64 + lane) * 16) = aG0;
            *(f32x4*)(scZ + ((1 * 8 + wv) * 64 + lane) * 16) = aG1;
        }
        __syncthreads();

        // ---- g reduce + h update
        {
            float sg = 0.f;
#pragma unroll
            for (int ww = 0; ww < 8; ++ww)
                sg += *(const float*)(scZ + ((ntc * 8 + ww) * 64 + ls) * 16 + el * 4);
            sg += xls[((buf * 2 + tl) * 16 + b8) * 96 + 64 + n32] + biasG;
            float e  = __expf(-2.f * sg);
            float gt = 2.f / (1.f + e) - 1.f;
            float hn = zval * h_own + (1.f - zval) * gt;
            h_own = hn;
            tmp16[b8 * 32 + n32] = f2b(hn);
            if (layer == 1)
                hout[((long)(bg0 + b8) * 512 + tc) * 1024 + n0w + n32] = hn;
            if (tc == 511)
                hidden[(long)(bg0 + b8) * 2048 + layer * 1024 + n0w + n32] = hn;
        }
        __syncthreads();

        if (layer == 0 && tc >= 8)
            FLAGWAIT(f_h_l1, (u32)(tc - 8));    // ring slot tc&7 fully consumed

        PUBLISH(layer == 0
                    ? (char*)ring + (((tc & 7) * 64 + bg0) * 2048)
                    : (char*)hbG);
        FLAGREL(f_h + w * 16, (u32)(tc + 1));

        if (tl == 1 && prod) {
            __syncthreads();
            XWRITE(buf ^ 1);
        }
    }
}

// ---------------------------------------------------------------------------
// In-place output projection: y = h1 @ Why + by over h1 rows in d_out.
// ---------------------------------------------------------------------------
__global__ __launch_bounds__(256) void ygemm(const float* __restrict__ Why,
                                             const float* __restrict__ by,
                                             float* __restrict__ y)
{
    extern __shared__ char sm[];
    char* sA = sm;            // 64 rows x 2048B (bf16 k=1024)
    char* sW = sm + 131072;   // 128 n-rows x 128B

    const int tid  = threadIdx.x;
    const int lane = tid & 63;
    const int wv   = tid >> 6;
    const long r0  = (long)blockIdx.x * 64;

    for (int it = 0; it < 32; ++it) {
        int c = it * 256 + tid;
        int row = c >> 7, j = c & 127;
        long gi = (r0 + row) * 1024 + j * 8;
        float tp[8];
        *(uint4*)tp       = *(const uint4*)(y + gi);
        *(uint4*)(tp + 4) = *(const uint4*)(y + gi + 4);
        *(uint4*)(sA + row * 2048 + ((j * 16) ^ ((row & 7) << 4))) = pack8f(tp);
    }
    __syncthreads();

    for (int nt = 0; nt < 8; ++nt) {
        f32x4 acc[4][2] = {};
        for (int kt = 0; kt < 16; ++kt) {
            __syncthreads();
#pragma unroll
            for (int uu = 0; uu < 4; ++uu) {
                int u = uu * 256 + tid;
                int nrow = u >> 3, jc = u & 7;
                u16 e[8];
#pragma unroll
                for (int q = 0; q < 8; ++q)
                    e[q] = f2b(Why[(long)(kt * 64 + jc * 8 + q) * 1024 + nt * 128 + nrow]);
                uint4 v; __builtin_memcpy(&v, e, 16);
                *(uint4*)(sW + nrow * 128 + ((jc * 16) ^ ((nrow & 7) << 4))) = v;
            }
            __syncthreads();
#pragma unroll
            for (int ks = 0; ks < 2; ++ks) {
                int kbA = kt * 128 + ks * 64 + ((lane >> 4) << 4);
                int kbW = ks * 64 + ((lane >> 4) << 4);
#pragma unroll
                for (int cc = 0; cc < 2; ++cc) {
                    int brr = (wv * 2 + cc) * 16 + (lane & 15);
                    bf16x8 bF = *(const bf16x8*)(sW + brr * 128 + (kbW ^ ((brr & 7) << 4)));
#pragma unroll
                    for (int m = 0; m < 4; ++m) {
                        int ar = m * 16 + (lane & 15);
                        bf16x8 aF = *(const bf16x8*)(sA + ar * 2048 + (kbA ^ ((ar & 7) << 4)));
                        acc[m][cc] = __builtin_amdgcn_mfma_f32_16x16x32_bf16(
                            aF, bF, acc[m][cc], 0, 0, 0);
                    }
                }
            }
        }
#pragma unroll
        for (int cc = 0; cc < 2; ++cc) {
            int col = nt * 128 + (wv * 2 + cc) * 16 + (lane & 15);
            float bv = by[col];
#pragma unroll
            for (int m = 0; m < 4; ++m)
#pragma unroll
                for (int q = 0; q < 4; ++q) {
                    long row = r0 + m * 16 + ((lane >> 4) << 2) + q;
                    y[row * 1024 + col] = acc[m][cc][q] + bv;
                }
        }
    }
}

// ---------------------------------------------------------------------------
extern "C" void kernel_launch(void* const* d_in, const int* in_sizes, int n_in,
                              void* d_out, int out_size, void* d_ws,
                              size_t ws_size, hipStream_t stream) {
    const float* input = (const float*)d_in[0];
    const float* Wxz = (const float*)d_in[1];
    const float* Whz = (const float*)d_in[2];
    const float* bz  = (const float*)d_in[3];
    const float* Wxr = (const float*)d_in[4];
    const float* Whr = (const float*)d_in[5];
    const float* br  = (const float*)d_in[6];
    const float* Wxg = (const float*)d_in[7];
    const float* Whg = (const float*)d_in[8];
    const float* bg  = (const float*)d_in[9];
    const float* Why = (const float*)d_in[10];
    const float* by  = (const float*)d_in[11];
    (void)in_sizes; (void)n_in; (void)out_size; (void)ws_size;

    float* yreg   = (float*)d_out;            // [64][512][1024] h1 -> y
    float* hidden = yreg + 33554432;          // [64][2][1024]

    char* ws = (char*)d_ws;
    u32* flags = (u32*)ws;                    //  32768 B [2][4][2][512]
    u16* hb    = (u16*)(ws + 32768);          // 262144 B [2][4][16][1024]
    u16* rb    = (u16*)(ws + 294912);         // 262144 B
    u16* ring  = (u16*)(ws + 557056);         // 1048576 B [8][64][1024]

    hipFuncSetAttribute(reinterpret_cast<const void*>(gru_fused),
                        hipFuncAttributeMaxDynamicSharedMemorySize, SCAN_LDS);
    hipFuncSetAttribute(reinterpret_cast<const void*>(ygemm),
                        hipFuncAttributeMaxDynamicSharedMemorySize, YG_LDS);
    hipMemsetAsync(flags, 0, 32768, stream);

    gru_fused<<<256, 512, SCAN_LDS, stream>>>(
        input, Wxz, Wxr, Wxg, Whz, Whr, Whg, bz, br, bg,
        yreg, hidden, ring, hb, rb, flags);
    ygemm<<<512, 256, YG_LDS, stream>>>(Why, by, yreg);
}